// Round 26
// baseline (171.484 us; speedup 1.0000x reference)
//
#include <hip/hip_runtime.h>
#include <math.h>

#ifndef M_PI
#define M_PI 3.14159265358979323846
#endif

#define NJ    64      // 2*B_IN
#define NGRID 24
#define NB    16      // batch
#define FIN   64
#define FOUT  64
#define NOUTD 32      // 2*B_OUT
#define NHALF 2856    // sum_{l<16} (l+1)(2l+1)  (m>=0 half)
#define NH2   136     // sum_{l<16} (l+1)

typedef __attribute__((ext_vector_type(8))) short short8;
typedef __attribute__((ext_vector_type(4))) float f32x4;
typedef __attribute__((ext_vector_type(2))) float f32x2;

__device__ __forceinline__ int hoff(int l){ return l*(l+1)*(4*l-1)/6; }
__device__ __forceinline__ int h2off(int l){ return l*(l+1)/2; }

__device__ __forceinline__ void lm_from_s(int s, int& l, int& m){
  int ll = 0;
  while ((ll+1)*(ll+1) <= s) ll++;
  l = ll; m = s - ll*ll - ll;
}

// RNE bf16
__device__ __forceinline__ unsigned short f2bf(float x){
  unsigned int u = __float_as_uint(x);
  unsigned int r = (u + 0x7FFFu + ((u >> 16) & 1u)) >> 16;
  return (unsigned short)r;
}
// truncating bf16 (hot paths)
__device__ __forceinline__ unsigned short f2bt(float x){
  return (unsigned short)(__float_as_uint(x) >> 16);
}
__device__ __forceinline__ float bf2f(unsigned short h){
  return __uint_as_float(((unsigned int)h) << 16);
}

// swizzle: 16B-chunk XOR within a 64B row of 32 shorts; identical write & read.
__device__ __forceinline__ int swz(int r, int elem){
  return r*32 + ((((elem >> 3) ^ (r & 3)) << 3) | (elem & 7));
}

// Wigner small-d, quantum norm, CS phase. double precision.
__device__ double wigner_d_dev(int l, int mp, int m, double beta, const double* LF){
  double c = cos(0.5*beta), s = sin(0.5*beta);
  double lc = log(c), ls = log(s);
  double pref = 0.5*(LF[l+mp] + LF[l-mp] + LF[l+m] + LF[l-m]);
  int lo = max(0, m-mp), hi = min(l+m, l-mp);
  double v = 0.0;
  for (int k = lo; k <= hi; ++k){
    double lg = pref - (LF[l+m-k] + LF[k] + LF[mp-m+k] + LF[l-mp-k])
              + (double)(2*l + m - mp - 2*k) * lc + (double)(mp - m + 2*k) * ls;
    double t = exp(lg);
    v += ((mp - m + k) & 1) ? -t : t;
  }
  return v;
}

// ---- k0: LF + quadrature weights ----
__global__ void k0_consts(double* LF, double* wq){
  int t = threadIdx.x;
  if (t == 0){
    LF[0] = 0.0;
    double acc = 0.0;
    for (int i = 1; i < 70; ++i){ acc += log((double)i); LF[i] = acc; }
  }
  if (t < NJ){
    double b = 32.0;  // B_IN
    double sum = 0.0;
    for (int k = 0; k < 32; ++k)
      sum += sin((2.0*t+1.0)*(2.0*k+1.0)*M_PI/(4.0*b)) / (2.0*k+1.0);
    double a = (2.0/b) * sin(M_PI*(2.0*t+1.0)/(4.0*b)) * sum;
    wq[t] = a * M_PI / b;
  }
}

// ---- k1all: all constant tables in ONE launch (Wigner reflection symmetry).
// R26: Dtp stored as RNE bf16 — halves k6f's L2-bound Dtp traffic (1.07GB ->
// 535MB per dispatch; W is truncated to bf16 downstream anyway). ----
__global__ __launch_bounds__(256) void k1all(const double* __restrict__ LF, const double* __restrict__ wq,
                                             float* __restrict__ wig, float2* __restrict__ Fc,
                                             unsigned short* __restrict__ Dtpb, short* __restrict__ Epack,
                                             short* __restrict__ A2pack,
                                             const float* __restrict__ kern, float* __restrict__ kt){
  int b = blockIdx.x, tid = threadIdx.x;
  if (b < 32){
    int gid = b*256 + tid;
    int s = gid >> 5, j = gid & 31;
    int l, m; lm_from_s(s, l, m);
    double beta = (j + 0.5) * M_PI / (double)NJ;
    double d = wigner_d_dev(l, m, 0, beta, LF);
    float v = (float)(wq[j] * d);
    wig[s*NJ + j] = v;
    wig[s*NJ + (63 - j)] = ((l + m) & 1) ? -v : v;
  } else if (b < 56){
    int gid = (b - 32)*256 + tid;
    int s = gid / NGRID, a = gid % NGRID;
    int l, m; lm_from_s(s, l, m);
    int bidx = a / 8, aidx = a % 8;
    double beta  = (bidx + 1) * (M_PI / 8.0) / 3.0;
    double alpha = aidx * (M_PI / 4.0);
    double d  = wigner_d_dev(l, m, 0, beta, LF);
    double sq = sqrt((2.0*l + 1.0) / (4.0 * M_PI));
    Fc[s*NGRID + a] = make_float2((float)(sq*d*cos(m*alpha)), (float)(sq*d*sin(m*alpha)));
  } else if (b < 235){
    int gid = (b - 56)*256 + tid;
    if (gid < NHALF * 16){
      int idx = gid >> 4, j = gid & 15;
      int l = 0;
      while (hoff(l+1) <= idx) l++;
      int t = idx - hoff(l), nm = 2*l + 1;
      int m = t / nm, n = t % nm - l;
      double beta = (j + 0.5) * M_PI / (double)NOUTD;
      float v = (float)((2*l + 1) * wigner_d_dev(l, m, n, beta, LF));
      Dtpb[((size_t)(j >> 2) * NHALF + idx) * 4 + (j & 3)] = f2bf(v);
      int j2 = 31 - j, idx2 = idx - 2*n;
      Dtpb[((size_t)(j2 >> 2) * NHALF + idx2) * 4 + (j2 & 3)] = f2bf(((l + m) & 1) ? -v : v);
    }
  } else if (b < 247){
    int gid = (b - 235)*256 + tid;
    if (gid < 2048){
      int e = gid & 7, lane = (gid >> 3) & 63, mat = (gid >> 9) & 1, gt = (gid >> 10) & 1;
      int nn = (lane >> 4)*8 + e, g = gt*16 + (lane & 15);
      double v = 0.0;
      if (nn <= 30){
        double ang = 2.0 * M_PI * (double)((nn - 15) * g) / 32.0;
        v = mat ? sin(ang) : cos(ang);
      }
      unsigned short h = f2bf((float)v);
      float lo = (float)v - bf2f(h);
      Epack[((gt*2 + mat)*2 + 0)*512 + lane*8 + e] = (short)h;
      Epack[((gt*2 + mat)*2 + 1)*512 + lane*8 + e] = (short)f2bf(lo);
    } else if (gid < 3072){
      int g2 = gid - 2048;
      int e = g2 & 7, lane = (g2 >> 3) & 63, at = (g2 >> 9) & 1;
      int k = (lane >> 4)*8 + e, a = at*16 + (lane & 15);
      int m = k & 15;
      double s = (m == 0) ? 1.0 : 2.0;
      double ang = 2.0 * M_PI * (double)(m * a) / 32.0;
      double v = (k < 16) ? s * cos(ang) : -s * sin(ang);
      unsigned short h = f2bf((float)v);
      float lo = (float)v - bf2f(h);
      A2pack[(at*2 + 0)*512 + lane*8 + e] = (short)h;
      A2pack[(at*2 + 1)*512 + lane*8 + e] = (short)f2bf(lo);
    }
  } else {
    int o = b - 247;
    for (int t = tid; t < NGRID*64; t += 256){
      int a = t >> 6, i = t & 63;
      kt[(o*NGRID + a)*64 + i] = kern[(i*64 + o)*NGRID + a];
    }
  }
}

// ---- k234: fused k2+k3 (blocks < 1024) and k4 (blocks >= 1024) ----
__global__ __launch_bounds__(256) void k234(const float* __restrict__ x, const float* __restrict__ wig,
                                            float2* __restrict__ xhat,
                                            const float* __restrict__ kt, const float2* __restrict__ Fc,
                                            float2* __restrict__ yhc){
  __shared__ float  xt[64*65];
  __shared__ float2 xfs[16*65];
  __shared__ float2 tw[64];
  int bid = blockIdx.x;
  if (bid >= NB*FIN){
    int s = bid - NB*FIN;
    float2* fc = tw;
    if (threadIdx.x < NGRID) fc[threadIdx.x] = Fc[s*NGRID + threadIdx.x];
    __syncthreads();
    for (int p = threadIdx.x; p < FOUT*FIN; p += 256){
      int o = p >> 6, i = p & 63;
      float2 acc = make_float2(0.f, 0.f);
      for (int a = 0; a < NGRID; ++a){
        float k = kt[(o*NGRID + a)*64 + i];
        acc.x = fmaf(k, fc[a].x, acc.x);
        acc.y = fmaf(k, fc[a].y, acc.y);
      }
      yhc[(size_t)(s*FOUT + o)*FIN + i] = acc;
    }
    return;
  }
  int b = bid >> 6, i = bid & 63;
  const float* xp = x + (size_t)(b*64 + i) * 4096;
  for (int t = threadIdx.x; t < 4096; t += 256) xt[(t >> 6)*65 + (t & 63)] = xp[t];
  if (threadIdx.x < 64){
    float sv, cv;
    sincosf(-2.0f * (float)M_PI * threadIdx.x / 64.0f, &sv, &cv);
    tw[threadIdx.x] = make_float2(cv, sv);
  }
  __syncthreads();
  for (int t = threadIdx.x; t < 1024; t += 256){
    int mu = t >> 6, j = t & 63;
    float2 acc = make_float2(0.f, 0.f);
    const float* row = xt + j*65;
    int idx = 0;
    #pragma unroll 16
    for (int a = 0; a < 64; ++a){
      float2 wv = tw[idx];
      idx = (idx + mu) & 63;
      acc.x = fmaf(row[a], wv.x, acc.x);
      acc.y = fmaf(row[a], wv.y, acc.y);
    }
    xfs[mu*65 + j] = acc;
  }
  __syncthreads();
  if (threadIdx.x < NH2){
    int h = threadIdx.x;
    int l = 0;
    while (h2off(l+1) <= h) l++;
    int m = h - h2off(l);
    int s = l*l + l + m;
    const float4* wp = (const float4*)&wig[s*64];
    float2 acc = make_float2(0.f, 0.f);
    #pragma unroll 4
    for (int jq = 0; jq < 16; ++jq){
      float4 w4 = wp[jq];
      float2 v0 = xfs[m*65 + jq*4 + 0];
      float2 v1 = xfs[m*65 + jq*4 + 1];
      float2 v2 = xfs[m*65 + jq*4 + 2];
      float2 v3 = xfs[m*65 + jq*4 + 3];
      acc.x += w4.x*v0.x + w4.y*v1.x + w4.z*v2.x + w4.w*v3.x;
      acc.y += w4.x*v0.y + w4.y*v1.y + w4.z*v2.y + w4.w*v3.y;
    }
    xhat[(size_t)(h*16 + b)*64 + i] = acc;
  }
}

// ---- k5: MFMA complex contraction; nt-outer so B-fragments convert ONCE ----
__global__ __launch_bounds__(256) void k5_z(const float2* __restrict__ xhat, const float2* __restrict__ yhc,
                                            float2* __restrict__ Z, int b0, int chunk){
  int bid = blockIdx.x;
  int o = bid >> 4, l = bid & 15;
  int t21 = 2*l + 1;
  int nt2 = (t21 + 15) >> 4;
  int w = threadIdx.x >> 6, lane = threadIdx.x & 63;
  int q = lane >> 4, c = lane & 15;
  int bclamp = (b0 + c < NB) ? (b0 + c) : (NB - 1);

  for (int nt = 0; nt < nt2; ++nt){
    int n = nt*16 + c;
    int nc = n < t21 ? n : t21 - 1;
    const f32x4* bp = (const f32x4*)(yhc + ((size_t)((l*l + nc)*64 + o))*64);
    short8 brh[4], brl[4], bih[4], bil[4];
    #pragma unroll
    for (int kc = 0; kc < 4; ++kc){
      int v0 = kc*8 + q*2;
      f32x4 y0 = bp[v0], y1 = bp[v0 + 1];
      float yf[8] = {y0[0],y0[1],y0[2],y0[3],y1[0],y1[1],y1[2],y1[3]};
      unsigned short yh[8], yl[8];
      #pragma unroll
      for (int e = 0; e < 8; ++e){
        unsigned short h2 = f2bt(yf[e]);
        yh[e] = h2; yl[e] = f2bt(yf[e] - bf2f(h2));
      }
      #pragma unroll
      for (int e = 0; e < 8; e += 2){
        brh[kc][e]   = (short)yh[e];
        brl[kc][e]   = (short)yl[e];
        brh[kc][e+1] = (short)(yh[e+1] ^ 0x8000u);
        brl[kc][e+1] = (short)(yl[e+1] ^ 0x8000u);
        bih[kc][e]   = (short)yh[e+1];
        bil[kc][e]   = (short)yl[e+1];
        bih[kc][e+1] = (short)yh[e];
        bil[kc][e+1] = (short)yl[e];
      }
    }
    for (int mt = w; mt <= l; mt += 4){
      const f32x4* ap = (const f32x4*)(xhat + ((size_t)((h2off(l) + mt)*16 + bclamp))*64);
      f32x4 accr = {0.f,0.f,0.f,0.f}, acci = {0.f,0.f,0.f,0.f};
      #pragma unroll
      for (int kc = 0; kc < 4; ++kc){
        int v0 = kc*8 + q*2;
        f32x4 a0 = ap[v0], a1 = ap[v0 + 1];
        float af[8] = {a0[0],a0[1],a0[2],a0[3],a1[0],a1[1],a1[2],a1[3]};
        short8 ah, al;
        #pragma unroll
        for (int e = 0; e < 8; ++e){
          unsigned short h1 = f2bt(af[e]);
          ah[e] = (short)h1; al[e] = (short)f2bt(af[e] - bf2f(h1));
        }
        accr = __builtin_amdgcn_mfma_f32_16x16x32_bf16(ah, brh[kc], accr, 0, 0, 0);
        accr = __builtin_amdgcn_mfma_f32_16x16x32_bf16(al, brh[kc], accr, 0, 0, 0);
        accr = __builtin_amdgcn_mfma_f32_16x16x32_bf16(ah, brl[kc], accr, 0, 0, 0);
        acci = __builtin_amdgcn_mfma_f32_16x16x32_bf16(ah, bih[kc], acci, 0, 0, 0);
        acci = __builtin_amdgcn_mfma_f32_16x16x32_bf16(al, bih[kc], acci, 0, 0, 0);
        acci = __builtin_amdgcn_mfma_f32_16x16x32_bf16(ah, bil[kc], acci, 0, 0, 0);
      }
      if (n < t21){
        int idx = hoff(l) + mt*t21 + n;
        #pragma unroll
        for (int r = 0; r < 4; ++r){
          int bb = q*4 + r;
          if (bb < chunk){
            f32x2 v = {accr[r], acci[r]};
            __builtin_nontemporal_store(v, (f32x2*)(Z + (size_t)(bb*64 + o)*NHALF + idx));
          }
        }
      }
    }
  }
}

// ---- k6f: fused W-build + MFMA DFTs. R26: Dtp read as bf16 (8B/idx) —
// halves the L2-bound W-build traffic. Normal output stores (R25). ----
__global__ __launch_bounds__(512, 4) void k6f(const float2* __restrict__ Z, const unsigned short* __restrict__ Dtpb,
                                              const short* __restrict__ Epack, const short* __restrict__ A2pack,
                                              const float* __restrict__ bias, float* __restrict__ out, int b0){
  __shared__ float2 Zl[NHALF];                    // 22848 B
  __shared__ __align__(16) short Wfrag[2][2048];  //  8 KB (re-hi, im-hi)
  __shared__ __align__(16) short stag[4][1024];   //  8 KB (T hi only)
  __shared__ __align__(16) short Es[4096];        //  8 KB
  __shared__ __align__(16) short As[2048];        //  4 KB
  int o = blockIdx.x & 63, bloc = blockIdx.x >> 6;
  int tid = threadIdx.x;
  {
    const f32x4* zp4 = (const f32x4*)(Z + (size_t)(bloc*64 + o) * NHALF);
    f32x4* Zl4 = (f32x4*)Zl;
    for (int t = tid; t < NHALF/2; t += 512) Zl4[t] = __builtin_nontemporal_load(&zp4[t]);
  }
  ((short8*)Es)[tid & 511] = ((const short8*)Epack)[tid & 511];
  if (tid < 256) ((short8*)As)[tid] = ((const short8*)A2pack)[tid];

  int m = tid >> 5, nn = tid & 31;
  int n = nn - 15;
  int na = n < 0 ? -n : n;
  bool act = (nn < 31);
  int lmin = act ? (m > na ? m : na) : 16;
  int wsl = swz(m, nn);
  int idxc[16];
  float msk[16];
  #pragma unroll
  for (int l = 0; l < 16; ++l){
    int idx = hoff(l) + m*(2*l + 1) + n + l;
    idxc[l] = (l >= lmin) ? idx : 0;
    msk[l]  = (l >= lmin) ? 1.f : 0.f;
  }
  bool lowBatch = (m < 8);   // wave-uniform

  int w = tid >> 6, lane = tid & 63;
  int q = lane >> 4, mrow = lane & 15;
  int jw = w >> 1, half = w & 1;
  float bo = bias[o];
  const short8* EPs = (const short8*)Es;
  const short8* APs = (const short8*)As;
  const ushort4* DtV = (const ushort4*)Dtpb;   // [jc][idx] 4x bf16
  size_t obase = (size_t)((b0 + bloc)*64 + o) * 32768;
  short* sw = stag[jw];
  __syncthreads();

  for (int jc = 0; jc < 8; ++jc){
    float wr0 = 0.f, wr1 = 0.f, wr2 = 0.f, wr3 = 0.f;
    float wi0 = 0.f, wi1 = 0.f, wi2 = 0.f, wi3 = 0.f;
    if (lowBatch){
      ushort4 d4[8];
      float2 zv[8];
      #pragma unroll
      for (int e = 0; e < 8; ++e){
        d4[e] = DtV[(size_t)jc*NHALF + idxc[e]];
        zv[e] = Zl[idxc[e]];
      }
      #pragma unroll
      for (int e = 0; e < 8; ++e){
        float zx = zv[e].x * msk[e];
        float zy = zv[e].y * msk[e];
        float d0 = bf2f(d4[e].x), d1 = bf2f(d4[e].y), d2 = bf2f(d4[e].z), d3 = bf2f(d4[e].w);
        wr0 = fmaf(zx, d0, wr0); wi0 = fmaf(zy, d0, wi0);
        wr1 = fmaf(zx, d1, wr1); wi1 = fmaf(zy, d1, wi1);
        wr2 = fmaf(zx, d2, wr2); wi2 = fmaf(zy, d2, wi2);
        wr3 = fmaf(zx, d3, wr3); wi3 = fmaf(zy, d3, wi3);
      }
    }
    {
      ushort4 d4[8];
      float2 zv[8];
      #pragma unroll
      for (int e = 0; e < 8; ++e){
        d4[e] = DtV[(size_t)jc*NHALF + idxc[8 + e]];
        zv[e] = Zl[idxc[8 + e]];
      }
      #pragma unroll
      for (int e = 0; e < 8; ++e){
        float zx = zv[e].x * msk[8 + e];
        float zy = zv[e].y * msk[8 + e];
        float d0 = bf2f(d4[e].x), d1 = bf2f(d4[e].y), d2 = bf2f(d4[e].z), d3 = bf2f(d4[e].w);
        wr0 = fmaf(zx, d0, wr0); wi0 = fmaf(zy, d0, wi0);
        wr1 = fmaf(zx, d1, wr1); wi1 = fmaf(zy, d1, wi1);
        wr2 = fmaf(zx, d2, wr2); wi2 = fmaf(zy, d2, wi2);
        wr3 = fmaf(zx, d3, wr3); wi3 = fmaf(zy, d3, wi3);
      }
    }
    __syncthreads();
    {
      Wfrag[0][0*512 + wsl] = (short)f2bt(wr0); Wfrag[1][0*512 + wsl] = (short)f2bt(wi0);
      Wfrag[0][1*512 + wsl] = (short)f2bt(wr1); Wfrag[1][1*512 + wsl] = (short)f2bt(wi1);
      Wfrag[0][2*512 + wsl] = (short)f2bt(wr2); Wfrag[1][2*512 + wsl] = (short)f2bt(wi2);
      Wfrag[0][3*512 + wsl] = (short)f2bt(wr3); Wfrag[1][3*512 + wsl] = (short)f2bt(wi3);
    }
    __syncthreads();
    // phase 1
    {
      int gt = half;
      int fo = jw*512 + swz(mrow, 8*q);
      short8 wrh = *(const short8*)&Wfrag[0][fo];
      short8 wih = *(const short8*)&Wfrag[1][fo];
      short8 ech = EPs[((gt*2 + 0)*2 + 0)*64 + lane];
      short8 ecl = EPs[((gt*2 + 0)*2 + 1)*64 + lane];
      short8 esh = EPs[((gt*2 + 1)*2 + 0)*64 + lane];
      short8 esl = EPs[((gt*2 + 1)*2 + 1)*64 + lane];
      f32x4 ta = {0.f,0.f,0.f,0.f}, tb = {0.f,0.f,0.f,0.f}, ti = {0.f,0.f,0.f,0.f};
      ta = __builtin_amdgcn_mfma_f32_16x16x32_bf16(wrh, ech, ta, 0, 0, 0);
      ta = __builtin_amdgcn_mfma_f32_16x16x32_bf16(wrh, ecl, ta, 0, 0, 0);
      tb = __builtin_amdgcn_mfma_f32_16x16x32_bf16(wih, esh, tb, 0, 0, 0);
      tb = __builtin_amdgcn_mfma_f32_16x16x32_bf16(wih, esl, tb, 0, 0, 0);
      ti = __builtin_amdgcn_mfma_f32_16x16x32_bf16(wrh, esh, ti, 0, 0, 0);
      ti = __builtin_amdgcn_mfma_f32_16x16x32_bf16(wrh, esl, ti, 0, 0, 0);
      ti = __builtin_amdgcn_mfma_f32_16x16x32_bf16(wih, ech, ti, 0, 0, 0);
      ti = __builtin_amdgcn_mfma_f32_16x16x32_bf16(wih, ecl, ti, 0, 0, 0);
      int row = 16*gt + mrow;
      short4 pk0;
      {
        float t0 = ta[0] - tb[0], t1 = ta[1] - tb[1], t2 = ta[2] - tb[2], t3 = ta[3] - tb[3];
        pk0.x = (short)f2bt(t0); pk0.y = (short)f2bt(t1);
        pk0.z = (short)f2bt(t2); pk0.w = (short)f2bt(t3);
      }
      *(short4*)&sw[swz(row, 4*q)] = pk0;
      {
        pk0.x = (short)f2bt(ti[0]); pk0.y = (short)f2bt(ti[1]);
        pk0.z = (short)f2bt(ti[2]); pk0.w = (short)f2bt(ti[3]);
      }
      *(short4*)&sw[swz(row, 16 + 4*q)] = pk0;
    }
    __syncthreads();
    // phase 2 — normal stores (L2 merges half-lines)
    {
      int j = jc*4 + jw;
      float* op = out + obase + (size_t)j * 1024;
      short8 a2h = APs[(half*2 + 0)*64 + lane];
      short8 a2l = APs[(half*2 + 1)*64 + lane];
      #pragma unroll
      for (int gt = 0; gt < 2; ++gt){
        short8 bh = *(const short8*)&sw[swz(16*gt + mrow, 8*q)];
        f32x4 acc = {0.f,0.f,0.f,0.f};
        acc = __builtin_amdgcn_mfma_f32_16x16x32_bf16(a2h, bh, acc, 0, 0, 0);
        acc = __builtin_amdgcn_mfma_f32_16x16x32_bf16(a2l, bh, acc, 0, 0, 0);
        #pragma unroll
        for (int r = 0; r < 4; ++r)
          op[(16*half + 4*q + r)*32 + 16*gt + mrow] = acc[r] + bo;
      }
    }
  }
}

extern "C" void kernel_launch(void* const* d_in, const int* in_sizes, int n_in,
                              void* d_out, int out_size, void* d_ws, size_t ws_size,
                              hipStream_t stream){
  const float* x    = (const float*)d_in[0];
  const float* kern = (const float*)d_in[1];
  const float* bias = (const float*)d_in[2];
  float* out = (float*)d_out;

  char* ws = (char*)d_ws;
  size_t off = 0;
  auto alloc = [&](size_t bytes) -> char* {
    char* p = ws + off;
    off = (off + bytes + 511) & ~(size_t)511;
    return p;
  };
  double* LF   = (double*)alloc(70 * 8);
  double* wq   = (double*)alloc(64 * 8);
  float*  wig  = (float* )alloc((size_t)256 * NJ * 4);
  float2* Fc   = (float2*)alloc((size_t)256 * NGRID * 8);
  unsigned short* Dtpb = (unsigned short*)alloc((size_t)NHALF * 32 * 2);
  short*  Ep   = (short* )alloc(4096 * 2);
  short*  A2p  = (short* )alloc(2048 * 2);
  float*  kt   = (float* )alloc((size_t)FOUT * NGRID * 64 * 4);
  float2* xhat = (float2*)alloc((size_t)NH2 * NB * FIN * 8);
  float2* yhc  = (float2*)alloc((size_t)256 * FOUT * FIN * 8);
  size_t fixed = off;

  size_t zbytes_per_b = (size_t)FOUT * NHALF * 8;          // 1.46 MB
  int chunk = NB;
  while (chunk > 1 && fixed + (size_t)chunk * zbytes_per_b > ws_size) chunk >>= 1;
  float2* Z = (float2*)alloc((size_t)chunk * zbytes_per_b);

  hipLaunchKernelGGL(k0_consts, dim3(1), dim3(256), 0, stream, LF, wq);
  hipLaunchKernelGGL(k1all,    dim3(311), dim3(256), 0, stream, LF, wq, wig, Fc, Dtpb, Ep, A2p, kern, kt);
  hipLaunchKernelGGL(k234,     dim3(NB*FIN + 256), dim3(256), 0, stream, x, wig, xhat, kt, Fc, yhc);

  for (int b0 = 0; b0 < NB; b0 += chunk){
    hipLaunchKernelGGL(k5_z, dim3(FOUT*16), dim3(256), 0, stream, xhat, yhc, Z, b0, chunk);
    hipLaunchKernelGGL(k6f,  dim3(chunk*FOUT), dim3(512), 0, stream, Z, Dtpb, Ep, A2p, bias, out, b0);
  }
}

// Round 27
// 149.096 us; speedup vs baseline: 1.1502x; 1.1502x over previous
//
#include <hip/hip_runtime.h>
#include <math.h>

#ifndef M_PI
#define M_PI 3.14159265358979323846
#endif

#define NJ    64      // 2*B_IN
#define NGRID 24
#define NB    16      // batch
#define FIN   64
#define FOUT  64
#define NOUTD 32      // 2*B_OUT
#define NHALF 2856    // sum_{l<16} (l+1)(2l+1)  (m>=0 half)
#define NH2   136     // sum_{l<16} (l+1)

typedef __attribute__((ext_vector_type(8))) short short8;
typedef __attribute__((ext_vector_type(4))) float f32x4;
typedef __attribute__((ext_vector_type(2))) float f32x2;

__device__ __forceinline__ int hoff(int l){ return l*(l+1)*(4*l-1)/6; }
__device__ __forceinline__ int h2off(int l){ return l*(l+1)/2; }

__device__ __forceinline__ void lm_from_s(int s, int& l, int& m){
  int ll = 0;
  while ((ll+1)*(ll+1) <= s) ll++;
  l = ll; m = s - ll*ll - ll;
}

// RNE bf16
__device__ __forceinline__ unsigned short f2bf(float x){
  unsigned int u = __float_as_uint(x);
  unsigned int r = (u + 0x7FFFu + ((u >> 16) & 1u)) >> 16;
  return (unsigned short)r;
}
// truncating bf16 (hot paths)
__device__ __forceinline__ unsigned short f2bt(float x){
  return (unsigned short)(__float_as_uint(x) >> 16);
}
__device__ __forceinline__ float bf2f(unsigned short h){
  return __uint_as_float(((unsigned int)h) << 16);
}

// swizzle: 16B-chunk XOR within a 64B row of 32 shorts; identical write & read.
__device__ __forceinline__ int swz(int r, int elem){
  return r*32 + ((((elem >> 3) ^ (r & 3)) << 3) | (elem & 7));
}

// Wigner small-d, quantum norm, CS phase. double precision.
__device__ double wigner_d_dev(int l, int mp, int m, double beta, const double* LF){
  double c = cos(0.5*beta), s = sin(0.5*beta);
  double lc = log(c), ls = log(s);
  double pref = 0.5*(LF[l+mp] + LF[l-mp] + LF[l+m] + LF[l-m]);
  int lo = max(0, m-mp), hi = min(l+m, l-mp);
  double v = 0.0;
  for (int k = lo; k <= hi; ++k){
    double lg = pref - (LF[l+m-k] + LF[k] + LF[mp-m+k] + LF[l-mp-k])
              + (double)(2*l + m - mp - 2*k) * lc + (double)(mp - m + 2*k) * ls;
    double t = exp(lg);
    v += ((mp - m + k) & 1) ? -t : t;
  }
  return v;
}

// ---- k0: LF + quadrature weights ----
__global__ void k0_consts(double* LF, double* wq){
  int t = threadIdx.x;
  if (t == 0){
    LF[0] = 0.0;
    double acc = 0.0;
    for (int i = 1; i < 70; ++i){ acc += log((double)i); LF[i] = acc; }
  }
  if (t < NJ){
    double b = 32.0;  // B_IN
    double sum = 0.0;
    for (int k = 0; k < 32; ++k)
      sum += sin((2.0*t+1.0)*(2.0*k+1.0)*M_PI/(4.0*b)) / (2.0*k+1.0);
    double a = (2.0/b) * sin(M_PI*(2.0*t+1.0)/(4.0*b)) * sum;
    wq[t] = a * M_PI / b;
  }
}

// ---- k1all: all constant tables in ONE launch (Wigner reflection symmetry) ----
__global__ __launch_bounds__(256) void k1all(const double* __restrict__ LF, const double* __restrict__ wq,
                                             float* __restrict__ wig, float2* __restrict__ Fc,
                                             unsigned short* __restrict__ Dtpb, short* __restrict__ Epack,
                                             short* __restrict__ A2pack,
                                             const float* __restrict__ kern, float* __restrict__ kt){
  int b = blockIdx.x, tid = threadIdx.x;
  if (b < 32){
    int gid = b*256 + tid;
    int s = gid >> 5, j = gid & 31;
    int l, m; lm_from_s(s, l, m);
    double beta = (j + 0.5) * M_PI / (double)NJ;
    double d = wigner_d_dev(l, m, 0, beta, LF);
    float v = (float)(wq[j] * d);
    wig[s*NJ + j] = v;
    wig[s*NJ + (63 - j)] = ((l + m) & 1) ? -v : v;
  } else if (b < 56){
    int gid = (b - 32)*256 + tid;
    int s = gid / NGRID, a = gid % NGRID;
    int l, m; lm_from_s(s, l, m);
    int bidx = a / 8, aidx = a % 8;
    double beta  = (bidx + 1) * (M_PI / 8.0) / 3.0;
    double alpha = aidx * (M_PI / 4.0);
    double d  = wigner_d_dev(l, m, 0, beta, LF);
    double sq = sqrt((2.0*l + 1.0) / (4.0 * M_PI));
    Fc[s*NGRID + a] = make_float2((float)(sq*d*cos(m*alpha)), (float)(sq*d*sin(m*alpha)));
  } else if (b < 235){
    int gid = (b - 56)*256 + tid;
    if (gid < NHALF * 16){
      int idx = gid >> 4, j = gid & 15;
      int l = 0;
      while (hoff(l+1) <= idx) l++;
      int t = idx - hoff(l), nm = 2*l + 1;
      int m = t / nm, n = t % nm - l;
      double beta = (j + 0.5) * M_PI / (double)NOUTD;
      float v = (float)((2*l + 1) * wigner_d_dev(l, m, n, beta, LF));
      Dtpb[((size_t)(j >> 2) * NHALF + idx) * 4 + (j & 3)] = f2bf(v);
      int j2 = 31 - j, idx2 = idx - 2*n;
      Dtpb[((size_t)(j2 >> 2) * NHALF + idx2) * 4 + (j2 & 3)] = f2bf(((l + m) & 1) ? -v : v);
    }
  } else if (b < 247){
    int gid = (b - 235)*256 + tid;
    if (gid < 2048){
      int e = gid & 7, lane = (gid >> 3) & 63, mat = (gid >> 9) & 1, gt = (gid >> 10) & 1;
      int nn = (lane >> 4)*8 + e, g = gt*16 + (lane & 15);
      double v = 0.0;
      if (nn <= 30){
        double ang = 2.0 * M_PI * (double)((nn - 15) * g) / 32.0;
        v = mat ? sin(ang) : cos(ang);
      }
      unsigned short h = f2bf((float)v);
      float lo = (float)v - bf2f(h);
      Epack[((gt*2 + mat)*2 + 0)*512 + lane*8 + e] = (short)h;
      Epack[((gt*2 + mat)*2 + 1)*512 + lane*8 + e] = (short)f2bf(lo);
    } else if (gid < 3072){
      int g2 = gid - 2048;
      int e = g2 & 7, lane = (g2 >> 3) & 63, at = (g2 >> 9) & 1;
      int k = (lane >> 4)*8 + e, a = at*16 + (lane & 15);
      int m = k & 15;
      double s = (m == 0) ? 1.0 : 2.0;
      double ang = 2.0 * M_PI * (double)(m * a) / 32.0;
      double v = (k < 16) ? s * cos(ang) : -s * sin(ang);
      unsigned short h = f2bf((float)v);
      float lo = (float)v - bf2f(h);
      A2pack[(at*2 + 0)*512 + lane*8 + e] = (short)h;
      A2pack[(at*2 + 1)*512 + lane*8 + e] = (short)f2bf(lo);
    }
  } else {
    int o = b - 247;
    for (int t = tid; t < NGRID*64; t += 256){
      int a = t >> 6, i = t & 63;
      kt[(o*NGRID + a)*64 + i] = kern[(i*64 + o)*NGRID + a];
    }
  }
}

// ---- k234: fused k2+k3 (blocks < 1024) and k4 (blocks >= 1024) ----
__global__ __launch_bounds__(256) void k234(const float* __restrict__ x, const float* __restrict__ wig,
                                            float2* __restrict__ xhat,
                                            const float* __restrict__ kt, const float2* __restrict__ Fc,
                                            float2* __restrict__ yhc){
  __shared__ float  xt[64*65];
  __shared__ float2 xfs[16*65];
  __shared__ float2 tw[64];
  int bid = blockIdx.x;
  if (bid >= NB*FIN){
    int s = bid - NB*FIN;
    float2* fc = tw;
    if (threadIdx.x < NGRID) fc[threadIdx.x] = Fc[s*NGRID + threadIdx.x];
    __syncthreads();
    for (int p = threadIdx.x; p < FOUT*FIN; p += 256){
      int o = p >> 6, i = p & 63;
      float2 acc = make_float2(0.f, 0.f);
      for (int a = 0; a < NGRID; ++a){
        float k = kt[(o*NGRID + a)*64 + i];
        acc.x = fmaf(k, fc[a].x, acc.x);
        acc.y = fmaf(k, fc[a].y, acc.y);
      }
      yhc[(size_t)(s*FOUT + o)*FIN + i] = acc;
    }
    return;
  }
  int b = bid >> 6, i = bid & 63;
  const float* xp = x + (size_t)(b*64 + i) * 4096;
  for (int t = threadIdx.x; t < 4096; t += 256) xt[(t >> 6)*65 + (t & 63)] = xp[t];
  if (threadIdx.x < 64){
    float sv, cv;
    sincosf(-2.0f * (float)M_PI * threadIdx.x / 64.0f, &sv, &cv);
    tw[threadIdx.x] = make_float2(cv, sv);
  }
  __syncthreads();
  for (int t = threadIdx.x; t < 1024; t += 256){
    int mu = t >> 6, j = t & 63;
    float2 acc = make_float2(0.f, 0.f);
    const float* row = xt + j*65;
    int idx = 0;
    #pragma unroll 16
    for (int a = 0; a < 64; ++a){
      float2 wv = tw[idx];
      idx = (idx + mu) & 63;
      acc.x = fmaf(row[a], wv.x, acc.x);
      acc.y = fmaf(row[a], wv.y, acc.y);
    }
    xfs[mu*65 + j] = acc;
  }
  __syncthreads();
  if (threadIdx.x < NH2){
    int h = threadIdx.x;
    int l = 0;
    while (h2off(l+1) <= h) l++;
    int m = h - h2off(l);
    int s = l*l + l + m;
    const float4* wp = (const float4*)&wig[s*64];
    float2 acc = make_float2(0.f, 0.f);
    #pragma unroll 4
    for (int jq = 0; jq < 16; ++jq){
      float4 w4 = wp[jq];
      float2 v0 = xfs[m*65 + jq*4 + 0];
      float2 v1 = xfs[m*65 + jq*4 + 1];
      float2 v2 = xfs[m*65 + jq*4 + 2];
      float2 v3 = xfs[m*65 + jq*4 + 3];
      acc.x += w4.x*v0.x + w4.y*v1.x + w4.z*v2.x + w4.w*v3.x;
      acc.y += w4.x*v0.y + w4.y*v1.y + w4.z*v2.y + w4.w*v3.y;
    }
    xhat[(size_t)(h*16 + b)*64 + i] = acc;
  }
}

// ---- k5: MFMA complex contraction; nt-outer so B-fragments convert ONCE ----
__global__ __launch_bounds__(256) void k5_z(const float2* __restrict__ xhat, const float2* __restrict__ yhc,
                                            float2* __restrict__ Z, int b0, int chunk){
  int bid = blockIdx.x;
  int o = bid >> 4, l = bid & 15;
  int t21 = 2*l + 1;
  int nt2 = (t21 + 15) >> 4;
  int w = threadIdx.x >> 6, lane = threadIdx.x & 63;
  int q = lane >> 4, c = lane & 15;
  int bclamp = (b0 + c < NB) ? (b0 + c) : (NB - 1);

  for (int nt = 0; nt < nt2; ++nt){
    int n = nt*16 + c;
    int nc = n < t21 ? n : t21 - 1;
    const f32x4* bp = (const f32x4*)(yhc + ((size_t)((l*l + nc)*64 + o))*64);
    short8 brh[4], brl[4], bih[4], bil[4];
    #pragma unroll
    for (int kc = 0; kc < 4; ++kc){
      int v0 = kc*8 + q*2;
      f32x4 y0 = bp[v0], y1 = bp[v0 + 1];
      float yf[8] = {y0[0],y0[1],y0[2],y0[3],y1[0],y1[1],y1[2],y1[3]};
      unsigned short yh[8], yl[8];
      #pragma unroll
      for (int e = 0; e < 8; ++e){
        unsigned short h2 = f2bt(yf[e]);
        yh[e] = h2; yl[e] = f2bt(yf[e] - bf2f(h2));
      }
      #pragma unroll
      for (int e = 0; e < 8; e += 2){
        brh[kc][e]   = (short)yh[e];
        brl[kc][e]   = (short)yl[e];
        brh[kc][e+1] = (short)(yh[e+1] ^ 0x8000u);
        brl[kc][e+1] = (short)(yl[e+1] ^ 0x8000u);
        bih[kc][e]   = (short)yh[e+1];
        bil[kc][e]   = (short)yl[e+1];
        bih[kc][e+1] = (short)yh[e];
        bil[kc][e+1] = (short)yl[e];
      }
    }
    for (int mt = w; mt <= l; mt += 4){
      const f32x4* ap = (const f32x4*)(xhat + ((size_t)((h2off(l) + mt)*16 + bclamp))*64);
      f32x4 accr = {0.f,0.f,0.f,0.f}, acci = {0.f,0.f,0.f,0.f};
      #pragma unroll
      for (int kc = 0; kc < 4; ++kc){
        int v0 = kc*8 + q*2;
        f32x4 a0 = ap[v0], a1 = ap[v0 + 1];
        float af[8] = {a0[0],a0[1],a0[2],a0[3],a1[0],a1[1],a1[2],a1[3]};
        short8 ah, al;
        #pragma unroll
        for (int e = 0; e < 8; ++e){
          unsigned short h1 = f2bt(af[e]);
          ah[e] = (short)h1; al[e] = (short)f2bt(af[e] - bf2f(h1));
        }
        accr = __builtin_amdgcn_mfma_f32_16x16x32_bf16(ah, brh[kc], accr, 0, 0, 0);
        accr = __builtin_amdgcn_mfma_f32_16x16x32_bf16(al, brh[kc], accr, 0, 0, 0);
        accr = __builtin_amdgcn_mfma_f32_16x16x32_bf16(ah, brl[kc], accr, 0, 0, 0);
        acci = __builtin_amdgcn_mfma_f32_16x16x32_bf16(ah, bih[kc], acci, 0, 0, 0);
        acci = __builtin_amdgcn_mfma_f32_16x16x32_bf16(al, bih[kc], acci, 0, 0, 0);
        acci = __builtin_amdgcn_mfma_f32_16x16x32_bf16(ah, bil[kc], acci, 0, 0, 0);
      }
      if (n < t21){
        int idx = hoff(l) + mt*t21 + n;
        #pragma unroll
        for (int r = 0; r < 4; ++r){
          int bb = q*4 + r;
          if (bb < chunk){
            f32x2 v = {accr[r], acci[r]};
            __builtin_nontemporal_store(v, (f32x2*)(Z + (size_t)(bb*64 + o)*NHALF + idx));
          }
        }
      }
    }
  }
}

// ---- k6f: fused W-build + MFMA DFTs. R27: Zl stored as RNE-bf16 pairs
// (11.4KB vs 22.8KB) -> LDS 39.2KB -> 4 blocks/CU -> grid 1024 EXACTLY
// co-resident (kills the R26 3-blocks/CU 768+256 two-wave tail, ~33% waste). ----
__global__ __launch_bounds__(512, 4) void k6f(const float2* __restrict__ Z, const unsigned short* __restrict__ Dtpb,
                                              const short* __restrict__ Epack, const short* __restrict__ A2pack,
                                              const float* __restrict__ bias, float* __restrict__ out, int b0){
  __shared__ ushort2 Zlb[NHALF];                  // 11424 B (bf16 re, bf16 im)
  __shared__ __align__(16) short Wfrag[2][2048];  //  8 KB (re-hi, im-hi)
  __shared__ __align__(16) short stag[4][1024];   //  8 KB (T hi only)
  __shared__ __align__(16) short Es[4096];        //  8 KB
  __shared__ __align__(16) short As[2048];        //  4 KB
  int o = blockIdx.x & 63, bloc = blockIdx.x >> 6;
  int tid = threadIdx.x;
  {
    const f32x4* zp4 = (const f32x4*)(Z + (size_t)(bloc*64 + o) * NHALF);
    for (int t = tid; t < NHALF/2; t += 512){
      f32x4 zz = __builtin_nontemporal_load(&zp4[t]);
      Zlb[2*t + 0] = make_ushort2(f2bf(zz[0]), f2bf(zz[1]));
      Zlb[2*t + 1] = make_ushort2(f2bf(zz[2]), f2bf(zz[3]));
    }
  }
  ((short8*)Es)[tid & 511] = ((const short8*)Epack)[tid & 511];
  if (tid < 256) ((short8*)As)[tid] = ((const short8*)A2pack)[tid];

  int m = tid >> 5, nn = tid & 31;
  int n = nn - 15;
  int na = n < 0 ? -n : n;
  bool act = (nn < 31);
  int lmin = act ? (m > na ? m : na) : 16;
  int wsl = swz(m, nn);
  int idxc[16];
  float msk[16];
  #pragma unroll
  for (int l = 0; l < 16; ++l){
    int idx = hoff(l) + m*(2*l + 1) + n + l;
    idxc[l] = (l >= lmin) ? idx : 0;
    msk[l]  = (l >= lmin) ? 1.f : 0.f;
  }
  bool lowBatch = (m < 8);   // wave-uniform

  int w = tid >> 6, lane = tid & 63;
  int q = lane >> 4, mrow = lane & 15;
  int jw = w >> 1, half = w & 1;
  float bo = bias[o];
  const short8* EPs = (const short8*)Es;
  const short8* APs = (const short8*)As;
  const ushort4* DtV = (const ushort4*)Dtpb;   // [jc][idx] 4x bf16
  size_t obase = (size_t)((b0 + bloc)*64 + o) * 32768;
  short* sw = stag[jw];
  __syncthreads();

  for (int jc = 0; jc < 8; ++jc){
    float wr0 = 0.f, wr1 = 0.f, wr2 = 0.f, wr3 = 0.f;
    float wi0 = 0.f, wi1 = 0.f, wi2 = 0.f, wi3 = 0.f;
    if (lowBatch){
      ushort4 d4[8];
      ushort2 zv[8];
      #pragma unroll
      for (int e = 0; e < 8; ++e){
        d4[e] = DtV[(size_t)jc*NHALF + idxc[e]];
        zv[e] = Zlb[idxc[e]];
      }
      #pragma unroll
      for (int e = 0; e < 8; ++e){
        float zx = bf2f(zv[e].x) * msk[e];
        float zy = bf2f(zv[e].y) * msk[e];
        float d0 = bf2f(d4[e].x), d1 = bf2f(d4[e].y), d2 = bf2f(d4[e].z), d3 = bf2f(d4[e].w);
        wr0 = fmaf(zx, d0, wr0); wi0 = fmaf(zy, d0, wi0);
        wr1 = fmaf(zx, d1, wr1); wi1 = fmaf(zy, d1, wi1);
        wr2 = fmaf(zx, d2, wr2); wi2 = fmaf(zy, d2, wi2);
        wr3 = fmaf(zx, d3, wr3); wi3 = fmaf(zy, d3, wi3);
      }
    }
    {
      ushort4 d4[8];
      ushort2 zv[8];
      #pragma unroll
      for (int e = 0; e < 8; ++e){
        d4[e] = DtV[(size_t)jc*NHALF + idxc[8 + e]];
        zv[e] = Zlb[idxc[8 + e]];
      }
      #pragma unroll
      for (int e = 0; e < 8; ++e){
        float zx = bf2f(zv[e].x) * msk[8 + e];
        float zy = bf2f(zv[e].y) * msk[8 + e];
        float d0 = bf2f(d4[e].x), d1 = bf2f(d4[e].y), d2 = bf2f(d4[e].z), d3 = bf2f(d4[e].w);
        wr0 = fmaf(zx, d0, wr0); wi0 = fmaf(zy, d0, wi0);
        wr1 = fmaf(zx, d1, wr1); wi1 = fmaf(zy, d1, wi1);
        wr2 = fmaf(zx, d2, wr2); wi2 = fmaf(zy, d2, wi2);
        wr3 = fmaf(zx, d3, wr3); wi3 = fmaf(zy, d3, wi3);
      }
    }
    __syncthreads();
    {
      Wfrag[0][0*512 + wsl] = (short)f2bt(wr0); Wfrag[1][0*512 + wsl] = (short)f2bt(wi0);
      Wfrag[0][1*512 + wsl] = (short)f2bt(wr1); Wfrag[1][1*512 + wsl] = (short)f2bt(wi1);
      Wfrag[0][2*512 + wsl] = (short)f2bt(wr2); Wfrag[1][2*512 + wsl] = (short)f2bt(wi2);
      Wfrag[0][3*512 + wsl] = (short)f2bt(wr3); Wfrag[1][3*512 + wsl] = (short)f2bt(wi3);
    }
    __syncthreads();
    // phase 1
    {
      int gt = half;
      int fo = jw*512 + swz(mrow, 8*q);
      short8 wrh = *(const short8*)&Wfrag[0][fo];
      short8 wih = *(const short8*)&Wfrag[1][fo];
      short8 ech = EPs[((gt*2 + 0)*2 + 0)*64 + lane];
      short8 ecl = EPs[((gt*2 + 0)*2 + 1)*64 + lane];
      short8 esh = EPs[((gt*2 + 1)*2 + 0)*64 + lane];
      short8 esl = EPs[((gt*2 + 1)*2 + 1)*64 + lane];
      f32x4 ta = {0.f,0.f,0.f,0.f}, tb = {0.f,0.f,0.f,0.f}, ti = {0.f,0.f,0.f,0.f};
      ta = __builtin_amdgcn_mfma_f32_16x16x32_bf16(wrh, ech, ta, 0, 0, 0);
      ta = __builtin_amdgcn_mfma_f32_16x16x32_bf16(wrh, ecl, ta, 0, 0, 0);
      tb = __builtin_amdgcn_mfma_f32_16x16x32_bf16(wih, esh, tb, 0, 0, 0);
      tb = __builtin_amdgcn_mfma_f32_16x16x32_bf16(wih, esl, tb, 0, 0, 0);
      ti = __builtin_amdgcn_mfma_f32_16x16x32_bf16(wrh, esh, ti, 0, 0, 0);
      ti = __builtin_amdgcn_mfma_f32_16x16x32_bf16(wrh, esl, ti, 0, 0, 0);
      ti = __builtin_amdgcn_mfma_f32_16x16x32_bf16(wih, ech, ti, 0, 0, 0);
      ti = __builtin_amdgcn_mfma_f32_16x16x32_bf16(wih, ecl, ti, 0, 0, 0);
      int row = 16*gt + mrow;
      short4 pk0;
      {
        float t0 = ta[0] - tb[0], t1 = ta[1] - tb[1], t2 = ta[2] - tb[2], t3 = ta[3] - tb[3];
        pk0.x = (short)f2bt(t0); pk0.y = (short)f2bt(t1);
        pk0.z = (short)f2bt(t2); pk0.w = (short)f2bt(t3);
      }
      *(short4*)&sw[swz(row, 4*q)] = pk0;
      {
        pk0.x = (short)f2bt(ti[0]); pk0.y = (short)f2bt(ti[1]);
        pk0.z = (short)f2bt(ti[2]); pk0.w = (short)f2bt(ti[3]);
      }
      *(short4*)&sw[swz(row, 16 + 4*q)] = pk0;
    }
    __syncthreads();
    // phase 2 — normal stores (L2 merges half-lines)
    {
      int j = jc*4 + jw;
      float* op = out + obase + (size_t)j * 1024;
      short8 a2h = APs[(half*2 + 0)*64 + lane];
      short8 a2l = APs[(half*2 + 1)*64 + lane];
      #pragma unroll
      for (int gt = 0; gt < 2; ++gt){
        short8 bh = *(const short8*)&sw[swz(16*gt + mrow, 8*q)];
        f32x4 acc = {0.f,0.f,0.f,0.f};
        acc = __builtin_amdgcn_mfma_f32_16x16x32_bf16(a2h, bh, acc, 0, 0, 0);
        acc = __builtin_amdgcn_mfma_f32_16x16x32_bf16(a2l, bh, acc, 0, 0, 0);
        #pragma unroll
        for (int r = 0; r < 4; ++r)
          op[(16*half + 4*q + r)*32 + 16*gt + mrow] = acc[r] + bo;
      }
    }
  }
}

extern "C" void kernel_launch(void* const* d_in, const int* in_sizes, int n_in,
                              void* d_out, int out_size, void* d_ws, size_t ws_size,
                              hipStream_t stream){
  const float* x    = (const float*)d_in[0];
  const float* kern = (const float*)d_in[1];
  const float* bias = (const float*)d_in[2];
  float* out = (float*)d_out;

  char* ws = (char*)d_ws;
  size_t off = 0;
  auto alloc = [&](size_t bytes) -> char* {
    char* p = ws + off;
    off = (off + bytes + 511) & ~(size_t)511;
    return p;
  };
  double* LF   = (double*)alloc(70 * 8);
  double* wq   = (double*)alloc(64 * 8);
  float*  wig  = (float* )alloc((size_t)256 * NJ * 4);
  float2* Fc   = (float2*)alloc((size_t)256 * NGRID * 8);
  unsigned short* Dtpb = (unsigned short*)alloc((size_t)NHALF * 32 * 2);
  short*  Ep   = (short* )alloc(4096 * 2);
  short*  A2p  = (short* )alloc(2048 * 2);
  float*  kt   = (float* )alloc((size_t)FOUT * NGRID * 64 * 4);
  float2* xhat = (float2*)alloc((size_t)NH2 * NB * FIN * 8);
  float2* yhc  = (float2*)alloc((size_t)256 * FOUT * FIN * 8);
  size_t fixed = off;

  size_t zbytes_per_b = (size_t)FOUT * NHALF * 8;          // 1.46 MB
  int chunk = NB;
  while (chunk > 1 && fixed + (size_t)chunk * zbytes_per_b > ws_size) chunk >>= 1;
  float2* Z = (float2*)alloc((size_t)chunk * zbytes_per_b);

  hipLaunchKernelGGL(k0_consts, dim3(1), dim3(256), 0, stream, LF, wq);
  hipLaunchKernelGGL(k1all,    dim3(311), dim3(256), 0, stream, LF, wq, wig, Fc, Dtpb, Ep, A2p, kern, kt);
  hipLaunchKernelGGL(k234,     dim3(NB*FIN + 256), dim3(256), 0, stream, x, wig, xhat, kt, Fc, yhc);

  for (int b0 = 0; b0 < NB; b0 += chunk){
    hipLaunchKernelGGL(k5_z, dim3(FOUT*16), dim3(256), 0, stream, xhat, yhc, Z, b0, chunk);
    hipLaunchKernelGGL(k6f,  dim3(chunk*FOUT), dim3(512), 0, stream, Z, Dtpb, Ep, A2p, bias, out, b0);
  }
}